// Round 2
// baseline (146.734 us; speedup 1.0000x reference)
//
#include <hip/hip_runtime.h>
#include <math.h>

// TransformDomainInterpolator — wave-local register FFT, fully fused.
//
// One 2048-pt FFT per WAVE (64 lanes x 32 float2 regs), ownership
// n = r*64 + l.  Forward DIF:
//   d = 1024,512,256,128,64 : register pairs (r, r + d/64)
//   d = 32,16,8,4,2,1       : lane pairs (__shfl_xor by d) — no LDS, no barrier
// Pointwise half-shift filter in bit-reversed order:
//   k = rev6(l)<<5 | rev5(r), mult = sgn * e^{+i pi k/2048} / 2048,
//   sgn = -1 iff (l&1)   [matches verified kernel: angle rev8(u),rev3(j), j&1]
// Inverse DIT mirrors (d = 1..32 lanes, 64..1024 regs, conjugate twiddles).
// All twiddles direct __sincosf (one hw sincos per distinct angle; >= accuracy
// of the previous rotation-chain scheme).
//
// Block = 128 thr = 2 waves = 1 batch (wave w = symbol w); grid = batch = 512
// -> 2 blocks/CU, store burst of one block overlaps FFT of the other.
// Single __syncthreads: even/odd real parts staged in LDS, then verified-K2
// lerp epilogue (w = [0,0, 0/9..8/9, 1,1,1]) with float4 stores.
//
// Math identical to the 131.7us kernel: even[m] exact passthrough,
// odd = IDFT_2048(t_k * DFT_2048(x))/2048, t_k = +-e^{i pi k/2048}.

#define NSC  4096
#define PI_F 3.14159265358979323846f

__device__ __forceinline__ float2 cmulf(float2 a, float c, float s) {
  return make_float2(a.x * c - a.y * s, a.x * s + a.y * c);
}

__global__ __launch_bounds__(128)
void tdi_wave(const float* __restrict__ in_r,
              const float* __restrict__ in_i,
              float4* __restrict__ out) {
  __shared__ float even_sm[2][2048];
  __shared__ float odd_sm[2][2048];

  const int tid = threadIdx.x;
  const int l   = tid & 63;     // lane
  const int w   = tid >> 6;     // symbol 0/1
  const int b   = blockIdx.x;

  const float* __restrict__ pr = in_r + ((size_t)b << 12) + (w << 11);
  const float* __restrict__ pm = in_i + ((size_t)b << 12) + (w << 11);

  float2 x[32];

  // ---- load (coalesced: lane l reads n = 64r + l) + stash even reals ----
#pragma unroll
  for (int r = 0; r < 32; ++r) {
    const int n = (r << 6) | l;
    x[r] = make_float2(pr[n], pm[n]);
    even_sm[w][n] = x[r].x;
  }

  // ---- forward DIF, in-register stages d = 64e, e = 16,8,4,2,1 ----------
  // pair (r0, r0+e), r0&e==0:  lo = a+b ; hi = (a-b) * e^{-i pi (64j+l)/d},
  // j = r0 mod e.
#pragma unroll
  for (int e = 16; e >= 1; e >>= 1) {
    const float step = -PI_F / (float)(e * 64);
#pragma unroll
    for (int j = 0; j < e; ++j) {
      float s_, c_;
      __sincosf(step * (float)(64 * j + l), &s_, &c_);
#pragma unroll
      for (int g = 0; g < 32; g += 2 * e) {
        const int r0 = g + j, r1 = r0 + e;
        const float2 a = x[r0], bb = x[r1];
        x[r0] = make_float2(a.x + bb.x, a.y + bb.y);
        x[r1] = cmulf(make_float2(a.x - bb.x, a.y - bb.y), c_, s_);
      }
    }
  }

  // ---- forward DIF, cross-lane stages d = 32..1 -------------------------
  // new = (p + sg*x) * W_eff;  W = e^{-i pi (l&(d-1))/d} on upper lanes only.
#pragma unroll
  for (int d = 32; d >= 1; d >>= 1) {
    float s_, c_;
    __sincosf(-(PI_F / (float)d) * (float)(l & (d - 1)), &s_, &c_);
    const bool up = (l & d) != 0;
    const float Wc = up ? c_ : 1.f, Ws = up ? s_ : 0.f;
    const float sg = up ? -1.f : 1.f;
#pragma unroll
    for (int r = 0; r < 32; ++r) {
      const float px = __shfl_xor(x[r].x, d, 64);
      const float py = __shfl_xor(x[r].y, d, 64);
      const float tx = px + sg * x[r].x;
      const float ty = py + sg * x[r].y;
      x[r] = make_float2(tx * Wc - ty * Ws, tx * Ws + ty * Wc);
    }
  }

  // ---- pointwise filter (bit-reversed order) ----------------------------
  {
    const int rl6 = (int)(__brev((unsigned)l) >> 26);   // rev6(l)
    float sl, cl;
    __sincosf((PI_F / 64.f) * (float)rl6, &sl, &cl);
    const float sgn = (l & 1) ? -(1.f / 2048.f) : (1.f / 2048.f);
#pragma unroll
    for (int r = 0; r < 32; ++r) {
      const int rr = (int)(__brev((unsigned)r) >> 27);  // rev5(r)
      float sr, cr;
      __sincosf((PI_F / 2048.f) * (float)rr, &sr, &cr);
      const float fc = (cl * cr - sl * sr) * sgn;
      const float fs = (sl * cr + cl * sr) * sgn;
      x[r] = cmulf(x[r], fc, fs);
    }
  }

  // ---- inverse DIT, cross-lane stages d = 1..32 -------------------------
  // y = x * W_eff (upper only), W = e^{+i pi (l&(d-1))/d};  new = p + sg*y.
#pragma unroll
  for (int d = 1; d <= 32; d <<= 1) {
    float s_, c_;
    __sincosf((PI_F / (float)d) * (float)(l & (d - 1)), &s_, &c_);
    const bool up = (l & d) != 0;
    const float Wc = up ? c_ : 1.f, Ws = up ? s_ : 0.f;
    const float sg = up ? -1.f : 1.f;
#pragma unroll
    for (int r = 0; r < 32; ++r) {
      const float yx = x[r].x * Wc - x[r].y * Ws;
      const float yy = x[r].x * Ws + x[r].y * Wc;
      const float px = __shfl_xor(yx, d, 64);
      const float py = __shfl_xor(yy, d, 64);
      x[r] = make_float2(px + sg * yx, py + sg * yy);
    }
  }

  // ---- inverse DIT, in-register stages d = 64e, e = 1,2,4,8,16 ----------
  // t = x[r1] * e^{+i pi (64j+l)/d};  x[r1] = x[r0] - t;  x[r0] += t.
#pragma unroll
  for (int e = 1; e <= 16; e <<= 1) {
    const float step = PI_F / (float)(e * 64);
#pragma unroll
    for (int j = 0; j < e; ++j) {
      float s_, c_;
      __sincosf(step * (float)(64 * j + l), &s_, &c_);
#pragma unroll
      for (int g = 0; g < 32; g += 2 * e) {
        const int r0 = g + j, r1 = r0 + e;
        const float2 t = cmulf(x[r1], c_, s_);
        x[r1] = make_float2(x[r0].x - t.x, x[r0].y - t.y);
        x[r0] = make_float2(x[r0].x + t.x, x[r0].y + t.y);
      }
    }
  }

  // ---- stash odd reals (natural order), one barrier ---------------------
#pragma unroll
  for (int r = 0; r < 32; ++r) odd_sm[w][(r << 6) | l] = x[r].x;
  __syncthreads();

  // ---- epilogue: verified K2 lerp, float4 stores ------------------------
  float4* __restrict__ orow = out + (size_t)b * (14 * 1024);
#pragma unroll
  for (int e2 = 0; e2 < 8; ++e2) {
    const int q = tid + (e2 << 7);
    const float2 E0 = *(const float2*)&even_sm[0][2 * q];
    const float2 E1 = *(const float2*)&even_sm[1][2 * q];
    const float2 O0 = *(const float2*)&odd_sm[0][2 * q];
    const float2 O1 = *(const float2*)&odd_sm[1][2 * q];
#pragma unroll
    for (int t = 0; t < 14; ++t) {
      const float wt = (t < 2) ? 0.f : (t >= 11) ? 1.f : (float)(t - 2) * (1.f / 9.f);
      float4 v;
      v.x = E0.x + wt * (E1.x - E0.x);
      v.y = O0.x + wt * (O1.x - O0.x);
      v.z = E0.y + wt * (E1.y - E0.y);
      v.w = O0.y + wt * (O1.y - O0.y);
      orow[t * 1024 + q] = v;
    }
  }
}

extern "C" void kernel_launch(void* const* d_in, const int* in_sizes, int n_in,
                              void* d_out, int out_size, void* d_ws, size_t ws_size,
                              hipStream_t stream) {
  const float* hr = (const float*)d_in[0];
  const float* hi = (const float*)d_in[1];
  const int batch = in_sizes[0] / NSC;   // 512 for the reference config
  tdi_wave<<<dim3(batch), dim3(128), 0, stream>>>(hr, hi, (float4*)d_out);
}

// Round 4
// 133.975 us; speedup vs baseline: 1.0952x; 1.0952x over previous
//
#include <hip/hip_runtime.h>
#include <math.h>

// TransformDomainInterpolator — packed-real FFT (one 2048-pt complex FFT per
// batch instead of two), fused lerp epilogue.  [R3 resubmit: prior run died
// of an infra container failure, not a kernel verdict.]
//
// Key identity (t_k = sgn*e^{i pi k/2048}, sgn=-1 for k>=1024 — HW-verified):
//   t is Hermitian except t_1024 = -i.  For REAL input x, IDFT(t*DFT(x)) is
//   real up to an alternating term; x_i affects Re(odd) ONLY via the Nyquist
//   bin:  Re{IDFT(t*DFT(x_r + i x_i))}[n]
//     = HalfShift(x_r)[n] + (-1)^n * Sum_m((-1)^m x_i[m]) / 2048.
// So pack both symbols' REAL parts:  z = x_r0 + i*x_r1,  W = IDFT(t*DFT(z)):
//   odd0[n] = Re W[n] + (-1)^n * (S0_i - S1_r)/2048
//   odd1[n] = Im W[n] + (-1)^n * (S0_r + S1_i)/2048,   S^s = Sum (-1)^m x^s[m]
// FFT phase code (F1..F4 pointwise, I2..I4) is the verified R0 code verbatim
// (all linear in the input -> packing transparent; same absmax path).
//
// Block = 256 thr = 1 batch (one packed FFT), grid = batch = 512
// -> 2 blocks/CU, 2 independent barrier domains, 8 waves/CU.
// even[m] = in_r passthrough (exact); lerp w = [0,0, 0/9..8/9, 1,1,1].

#define NSC  4096
#define PI_F 3.14159265358979323846f
#define RSQ2 0.70710678118654752f

__device__ __forceinline__ int pada(int i) { return i + 2 * (i >> 5); }

__device__ __forceinline__ void bf_fwd(float2& a, float2& c, float tc, float ts) {
  const float tx = a.x - c.x, ty = a.y - c.y;
  a.x += c.x; a.y += c.y;
  c.x = tx * tc - ty * ts;
  c.y = tx * ts + ty * tc;
}
__device__ __forceinline__ void bf_inv(float2& a, float2& c, float tc, float ts) {
  const float tx = c.x * tc - c.y * ts, ty = c.x * ts + c.y * tc;
  c.x = a.x - tx; c.y = a.y - ty;
  a.x += tx; a.y += ty;
}

__device__ __forceinline__ void fwd3(float2* x, float c, float s) {
  bf_fwd(x[0], x[4], c, -s);
  { const float cj = RSQ2 * (c - s), sj = RSQ2 * (c + s);
    bf_fwd(x[1], x[5], cj, -sj); }
  bf_fwd(x[2], x[6], -s, -c);
  { const float cj = -RSQ2 * (s + c), sj = RSQ2 * (c - s);
    bf_fwd(x[3], x[7], cj, -sj); }
  const float c2 = c * c - s * s, s2 = 2.f * c * s;
  bf_fwd(x[0], x[2], c2, -s2);  bf_fwd(x[4], x[6], c2, -s2);
  bf_fwd(x[1], x[3], -s2, -c2); bf_fwd(x[5], x[7], -s2, -c2);
  const float c4 = c2 * c2 - s2 * s2, s4 = 2.f * c2 * s2;
  bf_fwd(x[0], x[1], c4, -s4); bf_fwd(x[2], x[3], c4, -s4);
  bf_fwd(x[4], x[5], c4, -s4); bf_fwd(x[6], x[7], c4, -s4);
}

__device__ __forceinline__ void inv3(float2* x, float c, float s) {
  const float c2 = c * c - s * s, s2 = 2.f * c * s;
  const float c4 = c2 * c2 - s2 * s2, s4 = 2.f * c2 * s2;
  bf_inv(x[0], x[1], c4, s4); bf_inv(x[2], x[3], c4, s4);
  bf_inv(x[4], x[5], c4, s4); bf_inv(x[6], x[7], c4, s4);
  bf_inv(x[0], x[2], c2, s2);  bf_inv(x[4], x[6], c2, s2);
  bf_inv(x[1], x[3], -s2, c2); bf_inv(x[5], x[7], -s2, c2);
  bf_inv(x[0], x[4], c, s);
  { const float cj = RSQ2 * (c - s), sj = RSQ2 * (c + s);
    bf_inv(x[1], x[5], cj, sj); }
  bf_inv(x[2], x[6], -s, c);
  { const float cj = -RSQ2 * (s + c), sj = RSQ2 * (c - s);
    bf_inv(x[3], x[7], cj, sj); }
}

__global__ __launch_bounds__(256)
void tdi_pk(const float* __restrict__ in_r,
            const float* __restrict__ in_i,
            float4* __restrict__ out) {
  __shared__ __align__(16) float2 As[2176];   // 2048 + pad
  __shared__ float sred[4][4];                // [wave][S0r,S1r,S0i,S1i]

  const int u = threadIdx.x;                  // 0..255
  const int b = blockIdx.x;

  const float* __restrict__ pr0 = in_r + ((size_t)b << 12);
  const float* __restrict__ pr1 = pr0 + 2048;
  const float* __restrict__ pi0 = in_i + ((size_t)b << 12);
  const float* __restrict__ pi1 = pi0 + 2048;

  float2 x[8];
  float s, c;

  // ---- F1: load packed z = (xr0, xr1); alternating sums; fwd stages 10,9,8
  float a_r0 = 0.f, a_r1 = 0.f, a_i0 = 0.f, a_i1 = 0.f;
#pragma unroll
  for (int j = 0; j < 8; ++j) {
    const int n = u + 256 * j;
    x[j] = make_float2(pr0[n], pr1[n]);
    a_r0 += x[j].x;  a_r1 += x[j].y;
    a_i0 += pi0[n];  a_i1 += pi1[n];
  }
  {
    // sign (-1)^n with n = u + 256j  ->  (-1)^u, constant per thread
    const float sg = (u & 1) ? -1.f : 1.f;
    a_r0 *= sg; a_r1 *= sg; a_i0 *= sg; a_i1 *= sg;
#pragma unroll
    for (int off = 32; off >= 1; off >>= 1) {
      a_r0 += __shfl_xor(a_r0, off, 64);
      a_r1 += __shfl_xor(a_r1, off, 64);
      a_i0 += __shfl_xor(a_i0, off, 64);
      a_i1 += __shfl_xor(a_i1, off, 64);
    }
    if ((u & 63) == 0) {
      const int w = u >> 6;
      sred[w][0] = a_r0; sred[w][1] = a_r1;
      sred[w][2] = a_i0; sred[w][3] = a_i1;
    }
  }
  __sincosf((float)u * (PI_F / 1024.f), &s, &c);
  fwd3(x, c, s);
#pragma unroll
  for (int j = 0; j < 8; ++j) As[pada(u + 256 * j)] = x[j];
  __syncthreads();

  // ---- F2: stages 7,6,5 --------------------------------------------------
  {
    const int q = u & 31;
    const int base = ((u >> 5) << 8) | q;
#pragma unroll
    for (int j = 0; j < 8; ++j) x[j] = As[pada(base + 32 * j)];
    __sincosf((float)q * (PI_F / 128.f), &s, &c);
    fwd3(x, c, s);
#pragma unroll
    for (int j = 0; j < 8; ++j) As[pada(base + 32 * j)] = x[j];
  }
  __syncthreads();

  // ---- F3: stages 4,3,2 --------------------------------------------------
  {
    const int q = u & 3;
    const int base = ((u >> 2) << 5) | q;
#pragma unroll
    for (int j = 0; j < 8; ++j) x[j] = As[pada(base + 4 * j)];
    __sincosf((float)q * (PI_F / 16.f), &s, &c);
    fwd3(x, c, s);
#pragma unroll
    for (int j = 0; j < 8; ++j) As[pada(base + 4 * j)] = x[j];
  }
  __syncthreads();

  // ---- F4: fwd stages 1,0 + pointwise t_k/2048 + inv stages 0,1 ---------
  {
    const int base = u << 3;
#pragma unroll
    for (int j = 0; j < 8; ++j) x[j] = As[pada(base + j)];
#pragma unroll
    for (int g = 0; g < 8; g += 4) {
      float2 t;
      t.x = x[g].x - x[g+2].x;  t.y = x[g].y - x[g+2].y;
      x[g].x += x[g+2].x;       x[g].y += x[g+2].y;
      x[g+2] = t;
      t.x = x[g+1].x - x[g+3].x; t.y = x[g+1].y - x[g+3].y;
      x[g+1].x += x[g+3].x;      x[g+1].y += x[g+3].y;
      x[g+3] = make_float2(t.y, -t.x);          // * (-i)
    }
#pragma unroll
    for (int g = 0; g < 8; g += 2) {
      float2 t;
      t.x = x[g].x - x[g+1].x; t.y = x[g].y - x[g+1].y;
      x[g].x += x[g+1].x;      x[g].y += x[g+1].y;
      x[g+1] = t;
    }
    {
      const float c8[8] = { 1.f,  0.92387953f,  0.70710678f,  0.38268343f,
                            0.f, -0.38268343f, -0.70710678f, -0.92387953f };
      const float s8[8] = { 0.f,  0.38268343f,  0.70710678f,  0.92387953f,
                            1.f,  0.92387953f,  0.70710678f,  0.38268343f };
      float cp, sp;
      __sincosf((float)(__brev((unsigned)u) >> 24) * (PI_F / 2048.f), &sp, &cp);
#pragma unroll
      for (int j = 0; j < 8; ++j) {
        const int rv = ((j & 1) << 2) | (j & 2) | (j >> 2);
        const float sc = (j & 1) ? -(1.f / 2048.f) : (1.f / 2048.f);
        const float fc = (cp * c8[rv] - sp * s8[rv]) * sc;
        const float fs = (sp * c8[rv] + cp * s8[rv]) * sc;
        const float2 a = x[j];
        x[j] = make_float2(a.x * fc - a.y * fs, a.x * fs + a.y * fc);
      }
    }
#pragma unroll
    for (int g = 0; g < 8; g += 2) {
      const float2 t = x[g+1];
      x[g+1].x = x[g].x - t.x; x[g+1].y = x[g].y - t.y;
      x[g].x  += t.x;          x[g].y  += t.y;
    }
#pragma unroll
    for (int g = 0; g < 8; g += 4) {
      float2 t = x[g+2];
      x[g+2].x = x[g].x - t.x; x[g+2].y = x[g].y - t.y;
      x[g].x  += t.x;          x[g].y  += t.y;
      t = make_float2(-x[g+3].y, x[g+3].x);     // * (+i)
      x[g+3].x = x[g+1].x - t.x; x[g+3].y = x[g+1].y - t.y;
      x[g+1].x += t.x;           x[g+1].y += t.y;
    }
#pragma unroll
    for (int j = 0; j < 8; ++j) As[pada(base + j)] = x[j];
  }
  __syncthreads();

  // ---- I2 ----------------------------------------------------------------
  {
    const int q = u & 3;
    const int base = ((u >> 2) << 5) | q;
#pragma unroll
    for (int j = 0; j < 8; ++j) x[j] = As[pada(base + 4 * j)];
    __sincosf((float)q * (PI_F / 16.f), &s, &c);
    inv3(x, c, s);
#pragma unroll
    for (int j = 0; j < 8; ++j) As[pada(base + 4 * j)] = x[j];
  }
  __syncthreads();

  // ---- I3 ----------------------------------------------------------------
  {
    const int q = u & 31;
    const int base = ((u >> 5) << 8) | q;
#pragma unroll
    for (int j = 0; j < 8; ++j) x[j] = As[pada(base + 32 * j)];
    __sincosf((float)q * (PI_F / 128.f), &s, &c);
    inv3(x, c, s);
#pragma unroll
    for (int j = 0; j < 8; ++j) As[pada(base + 32 * j)] = x[j];
  }
  __syncthreads();

  // ---- I4 ----------------------------------------------------------------
  {
#pragma unroll
    for (int j = 0; j < 8; ++j) x[j] = As[pada(u + 256 * j)];
    __sincosf((float)u * (PI_F / 1024.f), &s, &c);
    inv3(x, c, s);
#pragma unroll
    for (int j = 0; j < 8; ++j) As[pada(u + 256 * j)] = x[j];
  }
  __syncthreads();

  // ---- Epilogue: W -> odd0/odd1 with Nyquist corrections; lerp; store ----
  const float S0r = sred[0][0] + sred[1][0] + sred[2][0] + sred[3][0];
  const float S1r = sred[0][1] + sred[1][1] + sred[2][1] + sred[3][1];
  const float S0i = sred[0][2] + sred[1][2] + sred[2][2] + sred[3][2];
  const float S1i = sred[0][3] + sred[1][3] + sred[2][3] + sred[3][3];
  const float alpha = (S0i - S1r) * (1.f / 2048.f);   // odd0: +(-1)^n * alpha
  const float beta  = (S0r + S1i) * (1.f / 2048.f);   // odd1: +(-1)^n * beta

  float4* __restrict__ orow = out + (size_t)b * (14 * 1024);
#pragma unroll
  for (int e = 0; e < 4; ++e) {
    const int q = u + (e << 8);                 // 0..1023
    const float2 E0 = *(const float2*)&pr0[2 * q];
    const float2 E1 = *(const float2*)&pr1[2 * q];
    const float4 a  = *(const float4*)&As[pada(2 * q)];  // W[2q], W[2q+1]
    // n = 2q even -> +; n = 2q+1 odd -> -
    const float2 O0 = make_float2(a.x + alpha, a.z - alpha);
    const float2 O1 = make_float2(a.y + beta,  a.w - beta);
#pragma unroll
    for (int t = 0; t < 14; ++t) {
      const float wt = (t < 2) ? 0.f : (t >= 11) ? 1.f : (float)(t - 2) * (1.f / 9.f);
      float4 v;
      v.x = E0.x + wt * (E1.x - E0.x);
      v.y = O0.x + wt * (O1.x - O0.x);
      v.z = E0.y + wt * (E1.y - E0.y);
      v.w = O0.y + wt * (O1.y - O0.y);
      orow[t * 1024 + q] = v;
    }
  }
}

extern "C" void kernel_launch(void* const* d_in, const int* in_sizes, int n_in,
                              void* d_out, int out_size, void* d_ws, size_t ws_size,
                              hipStream_t stream) {
  const float* hr = (const float*)d_in[0];
  const float* hi = (const float*)d_in[1];
  const int batch = in_sizes[0] / NSC;   // 512 for the reference config
  tdi_pk<<<dim3(batch), dim3(256), 0, stream>>>(hr, hi, (float4*)d_out);
}